// Round 14
// baseline (127.255 us; speedup 1.0000x reference)
//
#include <hip/hip_runtime.h>
#include <math.h>

#define DV   256      // d_model
#define BB   64       // batch
#define LL   512      // seq len
#define DEG2 16       // 2 * n_degree
#define VV   8000     // vocab
#define CC   4        // n_category
#define LPW  4        // l's per wave
#define NW   4        // waves per block
#define NLC  32       // L-chunks (16 l per block-item)
#define NSL  2        // d-slices (2MB each)
#define NITEMS (BB*NLC)     // 2048 work items per slice
#define NE   (BB*LL*DEG2)   // 524288 edges
#define LN_EPS 1e-5f

typedef _Float16 half4 __attribute__((ext_vector_type(4)));
typedef _Float16 half8 __attribute__((ext_vector_type(8)));
typedef float    f32x2 __attribute__((ext_vector_type(2)));
typedef float    f32x4 __attribute__((ext_vector_type(4)));
typedef int      i32x4 __attribute__((ext_vector_type(4)));

__device__ __forceinline__ half8 sxor_h8(half8 v, int mask) {
    i32x4 i = __builtin_bit_cast(i32x4, v);
    i32x4 s;
    #pragma unroll
    for (int k = 0; k < 4; ++k) s[k] = __shfl_xor(i[k], mask);
    return __builtin_bit_cast(half8, s);
}

// ---------------- Kernel 1: LN the table -> fp16 sliced layout, + we_flat gather ----------------
__global__ void __launch_bounds__(64) ln_rows_kernel(
    const float* __restrict__ emb, const float* __restrict__ gamma,
    const float* __restrict__ beta,
    const int* __restrict__ w_edge, const float* __restrict__ we_table,
    half4* __restrict__ out, float* __restrict__ we_flat)
{
    const int row = blockIdx.x;
    const int ln  = threadIdx.x;

    // random we_table gather amortized across the grid (latency hides under LN)
    for (int g = blockIdx.x * 64 + ln; g < NE; g += VV * 64)
        we_flat[g] = we_table[w_edge[g]];

    const f32x4 v = ((const f32x4*)(emb + row * DV))[ln];

    float s = v[0] + v[1] + v[2] + v[3];
    #pragma unroll
    for (int off = 32; off > 0; off >>= 1) s += __shfl_xor(s, off);
    const float mu = s * (1.0f / DV);

    f32x4 c;
    #pragma unroll
    for (int k = 0; k < 4; ++k) c[k] = v[k] - mu;

    float q = c[0]*c[0] + c[1]*c[1] + c[2]*c[2] + c[3]*c[3];
    #pragma unroll
    for (int off = 32; off > 0; off >>= 1) q += __shfl_xor(q, off);
    const float rs = rsqrtf(q * (1.0f / DV) + LN_EPS);

    const f32x4 g  = ((const f32x4*)gamma)[ln];
    const f32x4 bt = ((const f32x4*)beta)[ln];

    half4 h;
    #pragma unroll
    for (int k = 0; k < 4; ++k) h[k] = (_Float16)(c[k] * rs * g[k] + bt[k]);

    const int sl = ln >> 5;                 // slice
    const int cc = ln & 31;                 // 8B chunk within slice
    ((half4*)out)[((size_t)sl * VV + row) * 32 + cc] = h;
}

// ---------------- Kernel 2: work-stealing, physical-XCD-pinned d-slices ----------------
// Block reads its hardware XCC_ID: XCDs 0-3 pop slice-0 items, XCDs 4-7 slice-1.
// Each XCD's table working set = one 2MB slice -> L2-resident (the actual test).
__global__ void __launch_bounds__(256) gnn_ws_kernel(
    const int*   __restrict__ nb_x,
    const int*   __restrict__ x,
    const float* __restrict__ we_flat,
    const float* __restrict__ eta_table,
    const half8* __restrict__ norm_emb,   // [NSL][VV][16 chunks of 16B]
    float*       __restrict__ h_part,     // [BB][NLC][DV]
    int*         __restrict__ counters)   // [2] zeroed each launch
{
    int xcc;
    asm volatile("s_getreg_b32 %0, hwreg(HW_REG_XCC_ID)" : "=s"(xcc));
    const int myslice = (xcc >> 2) & 1;

    const int tid = threadIdx.x;
    const int w   = tid >> 6;
    const int ln  = tid & 63;
    const int q   = ln >> 4;                   // lane group = row-within-quad
    const int c8  = ln & 15;                   // 16B chunk within row slice

    __shared__ int s_widx, s_slice;
    __shared__ float s_acc[NW][DV / NSL];

    for (;;) {
        __syncthreads();                       // protect s_widx/s_acc reuse
        if (tid == 0) {
            int v = atomicAdd(&counters[myslice], 1);
            int s = myslice;
            if (v >= NITEMS) {                 // own queue done -> steal
                v = atomicAdd(&counters[1 - myslice], 1);
                s = 1 - myslice;
            }
            s_widx = v; s_slice = s;
        }
        __syncthreads();
        const int widx = s_widx;
        const int sl   = s_slice;
        if (widx >= NITEMS) return;

        const int b  = widx >> 5;
        const int lc = widx & 31;

        const int l0   = lc * 16 + w * LPW;
        const int base = b * LL + l0;
        const size_t sRow = (size_t)sl * VV;

        const int   nbv = __builtin_nontemporal_load(nb_x    + base * DEG2 + ln);
        const float wev = __builtin_nontemporal_load(we_flat + base * DEG2 + ln);

        int xv = 0; float etv = 0.0f;
        if (ln < LPW) { xv = x[base + ln]; etv = eta_table[xv]; }

        // self rows: group q handles l = l0+q  (divergent q -> __shfl, not readlane)
        const int   srow = __shfl(xv, q);
        const half8 se   = norm_emb[(sRow + srow) * 16 + c8];
        const float eta  = __shfl(etv, q);
        const float om   = 1.0f - eta;

        float acc[8] = {0,0,0,0,0,0,0,0};

        #pragma unroll
        for (int li = 0; li < LPW; ++li) {
            half8 m;
            #pragma unroll
            for (int k = 0; k < 8; ++k) m[k] = (_Float16)(-65504.0f);

            #pragma unroll
            for (int k4 = 0; k4 < 4; ++k4) {
                const int   jsrc = li * DEG2 + k4 * 4 + q;
                const int   idx  = __shfl(nbv, jsrc);
                const float wj   = __shfl(wev, jsrc);
                half8 w8;
                #pragma unroll
                for (int t = 0; t < 8; ++t) w8[t] = (_Float16)wj;
                const half8 e = norm_emb[(sRow + idx) * 16 + c8];   // 4 rows / instr
                m = __builtin_elementwise_max(m, w8 * e);
            }
            m = __builtin_elementwise_max(m, sxor_h8(m, 16));
            m = __builtin_elementwise_max(m, sxor_h8(m, 32));

            if (q == li) {
                #pragma unroll
                for (int k = 0; k < 8; ++k)
                    acc[k] += om * (float)m[k] + eta * (float)se[k];
            }
        }

        #pragma unroll
        for (int k = 0; k < 8; ++k) {
            acc[k] += __shfl_xor(acc[k], 16);
            acc[k] += __shfl_xor(acc[k], 32);
        }

        if (ln < 16) {
            f32x4 a0 = {acc[0], acc[1], acc[2], acc[3]};
            f32x4 a1 = {acc[4], acc[5], acc[6], acc[7]};
            ((f32x4*)&s_acc[w][c8 * 8])[0] = a0;
            ((f32x4*)&s_acc[w][c8 * 8])[1] = a1;
        }
        __syncthreads();
        if (w == 0) {
            const int d2 = ln * 2;
            f32x2 r;
            r[0] = s_acc[0][d2]     + s_acc[1][d2]     + s_acc[2][d2]     + s_acc[3][d2];
            r[1] = s_acc[0][d2 + 1] + s_acc[1][d2 + 1] + s_acc[2][d2 + 1] + s_acc[3][d2 + 1];
            __builtin_nontemporal_store(r,
                (f32x2*)(h_part + (size_t)(b * NLC + lc) * DV + sl * (DV / NSL)) + ln);
        }
    }
}

// ---------------- Kernel 3: reduce partials over lc, then FC ----------------
__global__ void __launch_bounds__(256) fc_kernel(
    const float* __restrict__ h_part,
    const float* __restrict__ fc_w,
    const float* __restrict__ fc_b,
    float*       __restrict__ out)
{
    const int b  = blockIdx.x;
    const int d  = threadIdx.x;
    const int w  = d >> 6;
    const int ln = d & 63;

    float h = 0.0f;
    #pragma unroll 8
    for (int lc = 0; lc < NLC; ++lc)
        h += h_part[(size_t)(b * NLC + lc) * DV + d];

    float p[CC];
    #pragma unroll
    for (int c = 0; c < CC; ++c) p[c] = h * fc_w[d * CC + c];

    #pragma unroll
    for (int c = 0; c < CC; ++c)
        #pragma unroll
        for (int off = 32; off > 0; off >>= 1) p[c] += __shfl_xor(p[c], off);

    __shared__ float s_red[NW][CC];
    if (ln == 0) {
        #pragma unroll
        for (int c = 0; c < CC; ++c) s_red[w][c] = p[c];
    }
    __syncthreads();
    if (d < CC)
        out[b * CC + d] = s_red[0][d] + s_red[1][d] + s_red[2][d] + s_red[3][d] + fc_b[d];
}

extern "C" void kernel_launch(void* const* d_in, const int* in_sizes, int n_in,
                              void* d_out, int out_size, void* d_ws, size_t ws_size,
                              hipStream_t stream) {
    const int*   x        = (const int*)  d_in[0];
    const int*   nb_x     = (const int*)  d_in[1];
    const int*   w_edge   = (const int*)  d_in[2];
    const float* emb_w    = (const float*)d_in[3];
    const float* we_table = (const float*)d_in[4];
    const float* eta_tab  = (const float*)d_in[5];
    const float* ln_gamma = (const float*)d_in[6];
    const float* ln_beta  = (const float*)d_in[7];
    const float* fc_w     = (const float*)d_in[8];
    const float* fc_b     = (const float*)d_in[9];
    float* out = (float*)d_out;

    // workspace layout
    char* ws = (char*)d_ws;
    half4* norm_emb = (half4*)(ws);                                 // 4,096,000 B
    float* we_flat  = (float*)(ws + 4096000);                       // 2,097,152 B
    float* h_part   = (float*)(ws + 4096000 + 2097152);             // 2,097,152 B
    int*   counters = (int*)  (ws + 4096000 + 2097152 + 2097152);   // 8 B

    hipMemsetAsync(counters, 0, 2 * sizeof(int), stream);   // deterministic queues

    ln_rows_kernel<<<VV, 64, 0, stream>>>(emb_w, ln_gamma, ln_beta,
                                          w_edge, we_table, norm_emb, we_flat);

    gnn_ws_kernel<<<2048, 256, 0, stream>>>(
        nb_x, x, we_flat, eta_tab, (const half8*)norm_emb, h_part, counters);

    fc_kernel<<<BB, 256, 0, stream>>>(h_part, fc_w, fc_b, out);
}

// Round 15
// 46.032 us; speedup vs baseline: 2.7645x; 2.7645x over previous
//
#include <hip/hip_runtime.h>
#include <math.h>

#define DV   256      // d_model
#define BB   64       // batch
#define LL   512      // seq len
#define DEG2 16       // 2 * n_degree
#define VV   8000     // vocab
#define CC   4        // n_category
#define LPW  4        // l's per wave
#define NW   4        // waves per block
#define NLC  32       // L-chunks (16 l per item)
#define NSL  2        // d-slices (2MB each)
#define IPB  2        // items per block
#define NE   (BB*LL*DEG2)   // 524288 edges
#define LN_EPS 1e-5f

typedef _Float16 half4 __attribute__((ext_vector_type(4)));
typedef _Float16 half8 __attribute__((ext_vector_type(8)));
typedef float    f32x2 __attribute__((ext_vector_type(2)));
typedef float    f32x4 __attribute__((ext_vector_type(4)));
typedef int      i32x4 __attribute__((ext_vector_type(4)));

__device__ __forceinline__ half8 sxor_h8(half8 v, int mask) {
    i32x4 i = __builtin_bit_cast(i32x4, v);
    i32x4 s;
    #pragma unroll
    for (int k = 0; k < 4; ++k) s[k] = __shfl_xor(i[k], mask);
    return __builtin_bit_cast(half8, s);
}

// ---------------- Kernel 1: LN the table -> fp16 sliced layout, + we_flat gather ----------------
// table layout: slice s holds d in [s*128, s*128+128): rows of 256B at (s*VV + row)
__global__ void __launch_bounds__(64) ln_rows_kernel(
    const float* __restrict__ emb, const float* __restrict__ gamma,
    const float* __restrict__ beta,
    const int* __restrict__ w_edge, const float* __restrict__ we_table,
    half4* __restrict__ out, float* __restrict__ we_flat)
{
    const int row = blockIdx.x;
    const int ln  = threadIdx.x;

    // random we_table gather amortized across the grid (latency hides under LN)
    for (int g = blockIdx.x * 64 + ln; g < NE; g += VV * 64)
        we_flat[g] = we_table[w_edge[g]];

    const f32x4 v = ((const f32x4*)(emb + row * DV))[ln];

    float s = v[0] + v[1] + v[2] + v[3];
    #pragma unroll
    for (int off = 32; off > 0; off >>= 1) s += __shfl_xor(s, off);
    const float mu = s * (1.0f / DV);

    f32x4 c;
    #pragma unroll
    for (int k = 0; k < 4; ++k) c[k] = v[k] - mu;

    float q = c[0]*c[0] + c[1]*c[1] + c[2]*c[2] + c[3]*c[3];
    #pragma unroll
    for (int off = 32; off > 0; off >>= 1) q += __shfl_xor(q, off);
    const float rs = rsqrtf(q * (1.0f / DV) + LN_EPS);

    const f32x4 g  = ((const f32x4*)gamma)[ln];
    const f32x4 bt = ((const f32x4*)beta)[ln];

    half4 h;
    #pragma unroll
    for (int k = 0; k < 4; ++k) h[k] = (_Float16)(c[k] * rs * g[k] + bt[k]);

    const int sl = ln >> 5;                 // slice
    const int cc = ln & 31;                 // 8B chunk within slice
    ((half4*)out)[((size_t)sl * VV + row) * 32 + cc] = h;
}

// ---------------- Kernel 2: static XCD-pinned d-slices, ONE scheduling generation ----------------
// 2048 blocks = 8/CU x 256 CU, all co-resident -> launch-order round-robin gives
// physical xcd = blk&7. XCDs 0-3 own slice 0 (d 0..127), XCDs 4-7 slice 1.
// Each XCD's table working set is 2MB -> half its L2. No atomics, no queue.
__global__ void __launch_bounds__(256) gnn_sliced_kernel(
    const int*   __restrict__ nb_x,
    const int*   __restrict__ x,
    const float* __restrict__ we_flat,
    const float* __restrict__ eta_table,
    const half8* __restrict__ norm_emb,   // [NSL][VV][16 chunks of 16B]
    float*       __restrict__ h_part)     // [BB][NLC][DV]
{
    const int blk = blockIdx.x;                  // 0..2047 (one generation)
    const int xcd = blk & 7;
    const int sl  = xcd >> 2;                    // this XCD's slice
    const int r   = ((blk >> 3) << 2) + (xcd & 3);   // 0..1023 rank within slice

    const int tid = threadIdx.x;
    const int w   = tid >> 6;
    const int ln  = tid & 63;
    const int q   = ln >> 4;                     // lane group = row-within-quad
    const int c8  = ln & 15;                     // 16B chunk within row slice

    const size_t sRow = (size_t)sl * VV;

    __shared__ float s_acc[NW][DV / NSL];

    #pragma unroll 1
    for (int i = 0; i < IPB; ++i) {
        const int it = r * IPB + i;              // 0..2047
        const int b  = it >> 5;
        const int lc = it & 31;

        const int l0   = lc * 16 + w * LPW;
        const int base = b * LL + l0;

        const int   nbv = __builtin_nontemporal_load(nb_x    + base * DEG2 + ln);
        const float wev = __builtin_nontemporal_load(we_flat + base * DEG2 + ln);

        int xv = 0; float etv = 0.0f;
        if (ln < LPW) { xv = x[base + ln]; etv = eta_table[xv]; }

        // self rows: group q handles l = l0+q  (divergent q -> __shfl, not readlane)
        const int   srow = __shfl(xv, q);
        const half8 se   = norm_emb[(sRow + srow) * 16 + c8];
        const float eta  = __shfl(etv, q);
        const float om   = 1.0f - eta;

        float acc[8] = {0,0,0,0,0,0,0,0};

        #pragma unroll
        for (int li = 0; li < LPW; ++li) {
            half8 m;
            #pragma unroll
            for (int k = 0; k < 8; ++k) m[k] = (_Float16)(-65504.0f);

            #pragma unroll
            for (int k4 = 0; k4 < 4; ++k4) {
                const int   jsrc = li * DEG2 + k4 * 4 + q;
                const int   idx  = __shfl(nbv, jsrc);
                const float wj   = __shfl(wev, jsrc);
                half8 w8;
                #pragma unroll
                for (int t = 0; t < 8; ++t) w8[t] = (_Float16)wj;
                const half8 e = norm_emb[(sRow + idx) * 16 + c8];   // 4 rows / instr
                m = __builtin_elementwise_max(m, w8 * e);
            }
            m = __builtin_elementwise_max(m, sxor_h8(m, 16));
            m = __builtin_elementwise_max(m, sxor_h8(m, 32));

            if (q == li) {
                #pragma unroll
                for (int k = 0; k < 8; ++k)
                    acc[k] += om * (float)m[k] + eta * (float)se[k];
            }
        }

        #pragma unroll
        for (int k = 0; k < 8; ++k) {
            acc[k] += __shfl_xor(acc[k], 16);
            acc[k] += __shfl_xor(acc[k], 32);
        }

        if (ln < 16) {
            f32x4 a0 = {acc[0], acc[1], acc[2], acc[3]};
            f32x4 a1 = {acc[4], acc[5], acc[6], acc[7]};
            ((f32x4*)&s_acc[w][c8 * 8])[0] = a0;
            ((f32x4*)&s_acc[w][c8 * 8])[1] = a1;
        }
        __syncthreads();
        if (w == 0) {
            const int d2 = ln * 2;
            f32x2 rr;
            rr[0] = s_acc[0][d2]     + s_acc[1][d2]     + s_acc[2][d2]     + s_acc[3][d2];
            rr[1] = s_acc[0][d2 + 1] + s_acc[1][d2 + 1] + s_acc[2][d2 + 1] + s_acc[3][d2 + 1];
            __builtin_nontemporal_store(rr,
                (f32x2*)(h_part + (size_t)(b * NLC + lc) * DV + sl * (DV / NSL)) + ln);
        }
        __syncthreads();   // s_acc safe to reuse next item
    }
}

// ---------------- Kernel 3: reduce partials over lc, then FC ----------------
__global__ void __launch_bounds__(256) fc_kernel(
    const float* __restrict__ h_part,
    const float* __restrict__ fc_w,
    const float* __restrict__ fc_b,
    float*       __restrict__ out)
{
    const int b  = blockIdx.x;
    const int d  = threadIdx.x;
    const int w  = d >> 6;
    const int ln = d & 63;

    float h = 0.0f;
    #pragma unroll 8
    for (int lc = 0; lc < NLC; ++lc)
        h += h_part[(size_t)(b * NLC + lc) * DV + d];

    float p[CC];
    #pragma unroll
    for (int c = 0; c < CC; ++c) p[c] = h * fc_w[d * CC + c];

    #pragma unroll
    for (int c = 0; c < CC; ++c)
        #pragma unroll
        for (int off = 32; off > 0; off >>= 1) p[c] += __shfl_xor(p[c], off);

    __shared__ float s_red[NW][CC];
    if (ln == 0) {
        #pragma unroll
        for (int c = 0; c < CC; ++c) s_red[w][c] = p[c];
    }
    __syncthreads();
    if (d < CC)
        out[b * CC + d] = s_red[0][d] + s_red[1][d] + s_red[2][d] + s_red[3][d] + fc_b[d];
}

extern "C" void kernel_launch(void* const* d_in, const int* in_sizes, int n_in,
                              void* d_out, int out_size, void* d_ws, size_t ws_size,
                              hipStream_t stream) {
    const int*   x        = (const int*)  d_in[0];
    const int*   nb_x     = (const int*)  d_in[1];
    const int*   w_edge   = (const int*)  d_in[2];
    const float* emb_w    = (const float*)d_in[3];
    const float* we_table = (const float*)d_in[4];
    const float* eta_tab  = (const float*)d_in[5];
    const float* ln_gamma = (const float*)d_in[6];
    const float* ln_beta  = (const float*)d_in[7];
    const float* fc_w     = (const float*)d_in[8];
    const float* fc_b     = (const float*)d_in[9];
    float* out = (float*)d_out;

    // workspace layout
    char* ws = (char*)d_ws;
    half4* norm_emb = (half4*)(ws);                      // 2*8000*256 = 4,096,000 B
    float* we_flat  = (float*)(ws + 4096000);            // 524288*4   = 2,097,152 B
    float* h_part   = (float*)(ws + 4096000 + 2097152);  // 64*32*256*4 = 2,097,152 B

    ln_rows_kernel<<<VV, 64, 0, stream>>>(emb_w, ln_gamma, ln_beta,
                                          w_edge, we_table, norm_emb, we_flat);

    gnn_sliced_kernel<<<2048, 256, 0, stream>>>(
        nb_x, x, we_flat, eta_tab, (const half8*)norm_emb, h_part);

    fc_kernel<<<BB, 256, 0, stream>>>(h_part, fc_w, fc_b, out);
}